// Round 3
// baseline (547.078 us; speedup 1.0000x reference)
//
#include <hip/hip_runtime.h>
#include <hip/hip_bf16.h>
#include <stdint.h>

typedef __bf16 bf16x8 __attribute__((ext_vector_type(8)));
typedef float f32x4 __attribute__((ext_vector_type(4)));

#define LOG2E 1.4426950408889634f

// ---------------- prep: build indices from batch_sizes ----------------
__global__ void prep_kernel(const int* __restrict__ bs, int T,
                            const int* __restrict__ sentences,
                            int* __restrict__ hdr, float* __restrict__ fhdr,
                            int* __restrict__ row_ctx, int* __restrict__ row_tok) {
    __shared__ int off[1025];
    if (threadIdx.x == 0) {
        int acc = 0; off[0] = 0;
        for (int t = 0; t < T; ++t) { acc += bs[t]; off[t + 1] = acc; }
    }
    __syncthreads();
    const int total = off[T];
    const int Nf = total - off[1];          // sum bs[1:]
    const int Nb = total - off[2];          // sum bs[2:]
    // forward: t = 1..T-1, ctx = off[t-1]+p, tgt = off[t]+p
    for (int t = 1; t < T; ++t) {
        int start = off[t] - off[1];
        int cnt = off[t + 1] - off[t];
        for (int p = threadIdx.x; p < cnt; p += blockDim.x) {
            row_ctx[start + p] = off[t - 1] + p;
            row_tok[start + p] = sentences[off[t] + p];
        }
    }
    // backward: i = 1..T-2, ctx = off[i+1]+p, tgt = off[i]+p
    for (int i = 1; i < T - 1; ++i) {
        int start = Nf + off[i + 1] - off[2];
        int cnt = off[i + 2] - off[i + 1];
        for (int p = threadIdx.x; p < cnt; p += blockDim.x) {
            row_ctx[start + p] = off[i + 1] + p;
            row_tok[start + p] = sentences[off[i] + p];
        }
    }
    if (threadIdx.x == 0) {
        hdr[0] = Nf + Nb;   // M_total
        hdr[1] = Nf;
        int bs0 = off[1];
        int bsl = off[T] - off[T - 1];
        fhdr[0] = (float)(2 * total - bs0 - bsl);  // denom
    }
}

// ---------------- W f32 -> bf16 ----------------
__global__ void wconv_kernel(const float* __restrict__ W,
                             __hip_bfloat16* __restrict__ Wb, long n4) {
    long i = (long)blockIdx.x * blockDim.x + threadIdx.x;
    if (i >= n4) return;
    float4 v = ((const float4*)W)[i];
    __hip_bfloat16 a0 = __float2bfloat16(v.x), a1 = __float2bfloat16(v.y);
    __hip_bfloat16 a2 = __float2bfloat16(v.z), a3 = __float2bfloat16(v.w);
    ushort4 pk;
    pk.x = *(unsigned short*)&a0; pk.y = *(unsigned short*)&a1;
    pk.z = *(unsigned short*)&a2; pk.w = *(unsigned short*)&a3;
    ((ushort4*)Wb)[i] = pk;
}

// ---------------- gather packed context rows -> bf16, zero S ----------------
__global__ void gather_kernel(const float* __restrict__ hs,
                              const int* __restrict__ row_ctx,
                              const int* __restrict__ hdr,
                              __hip_bfloat16* __restrict__ Hc,
                              float* __restrict__ S, int D2, int D) {
    const int m = blockIdx.x;
    const int M = hdr[0], Nf = hdr[1];
    const int Mpad = (M + 127) & ~127;
    if (m >= Mpad) return;
    if (threadIdx.x == 0) S[m] = 0.f;
    ushort4* dst = (ushort4*)(Hc + (size_t)m * D);
    if (m >= M) {
        ushort4 z; z.x = z.y = z.z = z.w = 0;
        for (int i = threadIdx.x; i < D / 4; i += blockDim.x) dst[i] = z;
        return;
    }
    const int ctx = row_ctx[m];
    const float4* src = (const float4*)(hs + (size_t)ctx * D2 + (m < Nf ? 0 : D));
    for (int i = threadIdx.x; i < D / 4; i += blockDim.x) {
        float4 v = src[i];
        __hip_bfloat16 a0 = __float2bfloat16(v.x), a1 = __float2bfloat16(v.y);
        __hip_bfloat16 a2 = __float2bfloat16(v.z), a3 = __float2bfloat16(v.w);
        ushort4 pk;
        pk.x = *(unsigned short*)&a0; pk.y = *(unsigned short*)&a1;
        pk.z = *(unsigned short*)&a2; pk.w = *(unsigned short*)&a3;
        dst[i] = pk;
    }
}

// ---------------- main GEMM + sum-exp epilogue ----------------
// C[m][v] = sum_k Hc[m][k] * W[v][k]; S[m] += sum_v exp(C[m][v] + bias[v])
//
// LDS layout (conflict-free, verified r2: SQ_LDS_BANK_CONFLICT=0): 512 x 16B
// chunks in fragment-read order; fragment read = base + mf*1024 + lane*16
// (contiguous 1024B wave access). Permutation lives in the per-lane GLOBAL
// source address; global_load_lds dest stays linear (rule #21).
//
// Pipeline (T4, counted vmcnt — never drain to 0 in the loop): 3 buffers,
// 3 tiles in flight. Per K-step:
//   s_waitcnt vmcnt(8)  -> own 4 loads of tile t landed (t+1,t+2 in flight)
//   s_barrier           -> all waves' contributions to buf[t] are in
//   compute(buf[t])     -> ds_read+MFMA (lgkmcnt handled by compiler)
//   s_barrier           -> all waves done READING buf[t]
//   stage(buf[t], t+3)  -> refill; ~2 iterations of latency budget
template <bool CONVB>
__global__ __launch_bounds__(256, 2)
void gemm_lse_kernel(const __hip_bfloat16* __restrict__ A,
                     const void* __restrict__ Bvoid,
                     const float* __restrict__ fb,
                     const float* __restrict__ bb,
                     float* __restrict__ S,
                     const int* __restrict__ hdr, int K, int MT) {
    const int M = hdr[0], Nf = hdr[1];

    // XCD-aware bijective swizzle (m204), bm-fastest: blocks sharing a W-tile
    // (same bn) run on one XCD (r2: FETCH 962->650 MB).
    const int nwg = gridDim.x;
    const int orig = blockIdx.x;
    const int q = nwg >> 3, r = nwg & 7;
    const int xcd = orig & 7, i8 = orig >> 3;
    const int wgid = (xcd < r ? xcd * (q + 1) : r * (q + 1) + (xcd - r) * q) + i8;
    const int bm = wgid % MT;
    const int bn = wgid / MT;
    if (bm * 128 >= M) return;

    __shared__ __align__(16) char lA[3][8192];
    __shared__ __align__(16) char lB[3][8192];

    const int tid = threadIdx.x;
    const int wid = tid >> 6, lane = tid & 63;
    const int wm = wid >> 1, wn = wid & 1;

    f32x4 acc[4][4];
#pragma unroll
    for (int i = 0; i < 4; ++i)
#pragma unroll
        for (int j = 0; j < 4; ++j) acc[i][j] = (f32x4)0.f;

    const char* gA = (const char*)(A + (size_t)bm * 128 * K);
    const __hip_bfloat16* Bb = (const __hip_bfloat16*)Bvoid;
    const float* Bf = (const float*)Bvoid;
    const char* gB = (const char*)(Bb + (size_t)bn * 128 * K);
    const int Kb = K * 2;  // bf16 row stride in bytes

    // staging geometry: chunk i = j*256 + tid
    // -> global row ((i>>6)<<4)|(i&15), k-group (i>>4)&3, LDS byte i*16
    int srow[2], skg[2];
#pragma unroll
    for (int j = 0; j < 2; ++j) {
        const int i = j * 256 + tid;
        srow[j] = ((i >> 6) << 4) | (i & 15);
        skg[j] = (i >> 4) & 3;
    }

    auto stage = [&](int buf, int t) {
        const int ktb = t << 6;  // 64 bytes of K per step
#pragma unroll
        for (int j = 0; j < 2; ++j) {
            const int i = j * 256 + tid;
            __builtin_amdgcn_global_load_lds(
                (const __attribute__((address_space(1))) uint32_t*)(gA + (size_t)srow[j] * Kb + ktb + skg[j] * 16),
                (__attribute__((address_space(3))) uint32_t*)(lA[buf] + i * 16), 16, 0, 0);
            __builtin_amdgcn_global_load_lds(
                (const __attribute__((address_space(1))) uint32_t*)(gB + (size_t)srow[j] * Kb + ktb + skg[j] * 16),
                (__attribute__((address_space(3))) uint32_t*)(lB[buf] + i * 16), 16, 0, 0);
        }
    };

    auto compute = [&](int buf) {
        bf16x8 a[4], b[4];
        const char* pa = lA[buf] + (lane << 4);
        const char* pb = lB[buf] + (lane << 4);
#pragma unroll
        for (int mf = 0; mf < 4; ++mf) a[mf] = *(const bf16x8*)(pa + ((wm * 4 + mf) << 10));
#pragma unroll
        for (int nf = 0; nf < 4; ++nf) b[nf] = *(const bf16x8*)(pb + ((wn * 4 + nf) << 10));
#pragma unroll
        for (int mf = 0; mf < 4; ++mf)
#pragma unroll
            for (int nf = 0; nf < 4; ++nf)
                acc[mf][nf] = __builtin_amdgcn_mfma_f32_16x16x32_bf16(a[mf], b[nf], acc[mf][nf], 0, 0, 0);
    };

    const int NT = K >> 5;  // K-steps of 32 (NT >= 4 required; K=1024 -> 32)

    if constexpr (CONVB) {
        // correctness fallback (W stays f32, converted during staging)
        for (int kt = 0; kt < NT; ++kt) {
            __syncthreads();
#pragma unroll
            for (int j = 0; j < 2; ++j) {
                const int i = j * 256 + tid;
                __builtin_amdgcn_global_load_lds(
                    (const __attribute__((address_space(1))) uint32_t*)(gA + (size_t)srow[j] * Kb + (kt << 6) + skg[j] * 16),
                    (__attribute__((address_space(3))) uint32_t*)(lA[0] + i * 16), 16, 0, 0);
                const float* src = Bf + (size_t)(bn * 128 + srow[j]) * K + (kt << 5) + skg[j] * 8;
                float4 v0 = *(const float4*)src, v1 = *(const float4*)(src + 4);
                union { __hip_bfloat16 h[8]; int4 i4; } u;
                u.h[0] = __float2bfloat16(v0.x); u.h[1] = __float2bfloat16(v0.y);
                u.h[2] = __float2bfloat16(v0.z); u.h[3] = __float2bfloat16(v0.w);
                u.h[4] = __float2bfloat16(v1.x); u.h[5] = __float2bfloat16(v1.y);
                u.h[6] = __float2bfloat16(v1.z); u.h[7] = __float2bfloat16(v1.w);
                *(int4*)(lB[0] + i * 16) = u.i4;
            }
            __syncthreads();
            compute(0);
        }
    } else {
        stage(0, 0); stage(1, 1); stage(2, 2);
        int cur = 0;
        for (int t = 0; t < NT - 3; ++t) {
            asm volatile("s_waitcnt vmcnt(8)" ::: "memory");
            __builtin_amdgcn_s_barrier();
            compute(cur);
            __builtin_amdgcn_s_barrier();
            stage(cur, t + 3);
            cur = (cur == 2) ? 0 : cur + 1;
        }
        // tail: t = NT-3, NT-2, NT-1 (no more staging; drain stepwise)
        asm volatile("s_waitcnt vmcnt(8)" ::: "memory");
        __builtin_amdgcn_s_barrier();
        compute(cur); cur = (cur == 2) ? 0 : cur + 1;
        asm volatile("s_waitcnt vmcnt(4)" ::: "memory");
        __builtin_amdgcn_s_barrier();
        compute(cur); cur = (cur == 2) ? 0 : cur + 1;
        asm volatile("s_waitcnt vmcnt(0)" ::: "memory");
        __builtin_amdgcn_s_barrier();
        compute(cur);
    }

    // epilogue: bias + exp + row-sum + atomic
    float fbv[4], bbv[4];
#pragma unroll
    for (int nf = 0; nf < 4; ++nf) {
        int v = bn * 128 + wn * 64 + nf * 16 + (lane & 15);
        fbv[nf] = fb[v]; bbv[nf] = bb[v];
    }
#pragma unroll
    for (int mf = 0; mf < 4; ++mf) {
#pragma unroll
        for (int j = 0; j < 4; ++j) {
            int m = bm * 128 + wm * 64 + mf * 16 + (lane >> 4) * 4 + j;
            if (m >= M) continue;   // uniform within each 16-lane shuffle group
            const bool isf = m < Nf;
            float ps = 0.f;
#pragma unroll
            for (int nf = 0; nf < 4; ++nf) {
                float logit = acc[mf][nf][j] + (isf ? fbv[nf] : bbv[nf]);
                ps += exp2f(logit * LOG2E);
            }
#pragma unroll
            for (int s = 1; s < 16; s <<= 1) ps += __shfl_xor(ps, s);
            if ((lane & 15) == 0) atomicAdd(&S[m], ps);
        }
    }
}

// ---------------- gold logits (exact f32) ----------------
__global__ void gold_kernel(const float* __restrict__ hs,
                            const float* __restrict__ W,
                            const float* __restrict__ fb,
                            const float* __restrict__ bb,
                            const int* __restrict__ row_ctx,
                            const int* __restrict__ row_tok,
                            const int* __restrict__ hdr,
                            float* __restrict__ goldv, int D2, int D) {
    const int m = blockIdx.x;
    const int M = hdr[0];
    if (m >= M) return;
    const int Nf = hdr[1];
    const int ctx = row_ctx[m], tok = row_tok[m];
    const float4* h = (const float4*)(hs + (size_t)ctx * D2 + (m < Nf ? 0 : D));
    const float4* w = (const float4*)(W + (size_t)tok * D);
    float s = 0.f;
    for (int i = threadIdx.x; i < D / 4; i += blockDim.x) {
        float4 a = h[i], b = w[i];
        s += a.x * b.x + a.y * b.y + a.z * b.z + a.w * b.w;
    }
#pragma unroll
    for (int d = 1; d < 64; d <<= 1) s += __shfl_xor(s, d);
    __shared__ float wsum[4];
    const int wid = threadIdx.x >> 6, lane = threadIdx.x & 63;
    if (lane == 0) wsum[wid] = s;
    __syncthreads();
    if (threadIdx.x == 0) {
        float tot = wsum[0] + wsum[1] + wsum[2] + wsum[3];
        tot += (m < Nf ? fb[tok] : bb[tok]);
        goldv[m] = tot;
    }
}

// ---------------- final reduce ----------------
__global__ void final_kernel(const float* __restrict__ S,
                             const float* __restrict__ goldv,
                             const int* __restrict__ hdr,
                             const float* __restrict__ fhdr,
                             float* __restrict__ out) {
    const int M = hdr[0];
    float s = 0.f;
    for (int m = threadIdx.x; m < M; m += blockDim.x)
        s += logf(S[m]) - goldv[m];
#pragma unroll
    for (int d = 1; d < 64; d <<= 1) s += __shfl_xor(s, d);
    __shared__ float wsum[4];
    const int wid = threadIdx.x >> 6, lane = threadIdx.x & 63;
    if (lane == 0) wsum[wid] = s;
    __syncthreads();
    if (threadIdx.x == 0)
        out[0] = (wsum[0] + wsum[1] + wsum[2] + wsum[3]) / fhdr[0];
}

extern "C" void kernel_launch(void* const* d_in, const int* in_sizes, int n_in,
                              void* d_out, int out_size, void* d_ws, size_t ws_size,
                              hipStream_t stream) {
    const float* hs  = (const float*)d_in[0];
    const float* W   = (const float*)d_in[1];
    const float* fb  = (const float*)d_in[2];
    const float* bb  = (const float*)d_in[3];
    const int* sent  = (const int*)d_in[4];
    const int* bs    = (const int*)d_in[5];
    const int total  = in_sizes[4];
    const int T      = in_sizes[5];
    const int V      = in_sizes[2];
    const int D      = in_sizes[1] / V;
    const int D2     = in_sizes[0] / total;
    const int Mcap   = ((2 * total) + 127) & ~127;   // upper bound on packed rows
    const int MT     = Mcap / 128;
    const int NN     = V / 128;

    char* p = (char*)d_ws;
    int*   hdr     = (int*)p;            p += 256;
    float* fhdr    = (float*)p;          p += 256;
    int*   row_ctx = (int*)p;            p += (size_t)Mcap * 4;
    int*   row_tok = (int*)p;            p += (size_t)Mcap * 4;
    float* S       = (float*)p;          p += (size_t)Mcap * 4;
    float* goldv   = (float*)p;          p += (size_t)Mcap * 4;
    __hip_bfloat16* Hc = (__hip_bfloat16*)p; p += (size_t)Mcap * D * 2;
    __hip_bfloat16* Wb = (__hip_bfloat16*)p;
    const size_t need_wb = (size_t)(p - (char*)d_ws) + (size_t)V * D * 2;

    prep_kernel<<<1, 256, 0, stream>>>(bs, T, sent, hdr, fhdr, row_ctx, row_tok);
    gather_kernel<<<Mcap, 256, 0, stream>>>(hs, row_ctx, hdr, Hc, S, D2, D);

    dim3 grid(NN * MT);
    if (ws_size >= need_wb) {
        long n4 = (long)V * D / 4;
        wconv_kernel<<<(int)((n4 + 255) / 256), 256, 0, stream>>>(W, Wb, n4);
        gemm_lse_kernel<false><<<grid, 256, 0, stream>>>(Hc, (const void*)Wb, fb, bb, S, hdr, D, MT);
    } else {
        gemm_lse_kernel<true><<<grid, 256, 0, stream>>>(Hc, (const void*)W, fb, bb, S, hdr, D, MT);
    }

    gold_kernel<<<Mcap, 256, 0, stream>>>(hs, W, fb, bb, row_ctx, row_tok, hdr, goldv, D2, D);
    final_kernel<<<1, 256, 0, stream>>>(S, goldv, hdr, fhdr, (float*)d_out);
}

// Round 4
// 482.297 us; speedup vs baseline: 1.1343x; 1.1343x over previous
//
#include <hip/hip_runtime.h>
#include <hip/hip_bf16.h>
#include <stdint.h>

typedef __bf16 bf16x8 __attribute__((ext_vector_type(8)));
typedef float f32x4 __attribute__((ext_vector_type(4)));

#define LOG2E 1.4426950408889634f
#define AS1 __attribute__((address_space(1)))
#define AS3 __attribute__((address_space(3)))

// ---------------- prep: build indices from batch_sizes ----------------
__global__ void prep_kernel(const int* __restrict__ bs, int T,
                            const int* __restrict__ sentences,
                            int* __restrict__ hdr, float* __restrict__ fhdr,
                            int* __restrict__ row_ctx, int* __restrict__ row_tok) {
    __shared__ int off[1025];
    if (threadIdx.x == 0) {
        int acc = 0; off[0] = 0;
        for (int t = 0; t < T; ++t) { acc += bs[t]; off[t + 1] = acc; }
    }
    __syncthreads();
    const int total = off[T];
    const int Nf = total - off[1];
    const int Nb = total - off[2];
    for (int t = 1; t < T; ++t) {
        int start = off[t] - off[1];
        int cnt = off[t + 1] - off[t];
        for (int p = threadIdx.x; p < cnt; p += blockDim.x) {
            row_ctx[start + p] = off[t - 1] + p;
            row_tok[start + p] = sentences[off[t] + p];
        }
    }
    for (int i = 1; i < T - 1; ++i) {
        int start = Nf + off[i + 1] - off[2];
        int cnt = off[i + 2] - off[i + 1];
        for (int p = threadIdx.x; p < cnt; p += blockDim.x) {
            row_ctx[start + p] = off[i + 1] + p;
            row_tok[start + p] = sentences[off[i] + p];
        }
    }
    if (threadIdx.x == 0) {
        hdr[0] = Nf + Nb;
        hdr[1] = Nf;
        int bs0 = off[1];
        int bsl = off[T] - off[T - 1];
        fhdr[0] = (float)(2 * total - bs0 - bsl);
    }
}

// ---------------- W f32 -> bf16 ----------------
__global__ void wconv_kernel(const float* __restrict__ W,
                             __hip_bfloat16* __restrict__ Wb, long n4) {
    long i = (long)blockIdx.x * blockDim.x + threadIdx.x;
    if (i >= n4) return;
    float4 v = ((const float4*)W)[i];
    __hip_bfloat16 a0 = __float2bfloat16(v.x), a1 = __float2bfloat16(v.y);
    __hip_bfloat16 a2 = __float2bfloat16(v.z), a3 = __float2bfloat16(v.w);
    ushort4 pk;
    pk.x = *(unsigned short*)&a0; pk.y = *(unsigned short*)&a1;
    pk.z = *(unsigned short*)&a2; pk.w = *(unsigned short*)&a3;
    ((ushort4*)Wb)[i] = pk;
}

// ---------------- gather packed context rows -> bf16, zero S ----------------
__global__ void gather_kernel(const float* __restrict__ hs,
                              const int* __restrict__ row_ctx,
                              const int* __restrict__ hdr,
                              __hip_bfloat16* __restrict__ Hc,
                              float* __restrict__ S, int D2, int D) {
    const int m = blockIdx.x;
    const int M = hdr[0], Nf = hdr[1];
    if (threadIdx.x == 0) S[m] = 0.f;
    ushort4* dst = (ushort4*)(Hc + (size_t)m * D);
    if (m >= M) {
        ushort4 z; z.x = z.y = z.z = z.w = 0;
        for (int i = threadIdx.x; i < D / 4; i += blockDim.x) dst[i] = z;
        return;
    }
    const int ctx = row_ctx[m];
    const float4* src = (const float4*)(hs + (size_t)ctx * D2 + (m < Nf ? 0 : D));
    for (int i = threadIdx.x; i < D / 4; i += blockDim.x) {
        float4 v = src[i];
        __hip_bfloat16 a0 = __float2bfloat16(v.x), a1 = __float2bfloat16(v.y);
        __hip_bfloat16 a2 = __float2bfloat16(v.z), a3 = __float2bfloat16(v.w);
        ushort4 pk;
        pk.x = *(unsigned short*)&a0; pk.y = *(unsigned short*)&a1;
        pk.z = *(unsigned short*)&a2; pk.w = *(unsigned short*)&a3;
        dst[i] = pk;
    }
}

// ---------------- main 256x256 / BK=64 / 8-wave / 8-phase GEMM + sum-exp ----------------
// C[m][v] = sum_k A[m][k] * B[v][k];  S[m] += sum_v exp(C + bias)
//
// Staging: per K-tile (BK=64), 4 "units" u=0..3, unit = k-quarter (16 k) of
// A(256 rows) + B(256 rows) = 8KB+8KB = 1 global_load_lds per thread per
// matrix. LDS stored in fragment-read order (r2/r3-verified conflict-free):
// within a unit, chunk i = block(i>>5)*... holds (row = (i>>5)*16+(i&15),
// khalf = (i>>4)&1); fragment read = two contiguous 512B wave segments.
//
// Schedule (T3+T4+T5, m201 regime): per K-tile, 4 phases of 16 MFMA each
// (ks-half x mf-half). Counted vmcnt(4) gates at phases 0 and 2 only:
// at every gate, exactly 2 units (4 loads) are newer than the unit needed,
// so vmcnt(4)+s_barrier guarantees all waves' contributions landed.
// Stage of tile t+1 unit u issues in phase u of tile t -> 3-4 phases of
// latency slack, never drains to 0 until the peeled last tile.
__global__ __launch_bounds__(512, 2)
void gemm_lse_256(const __hip_bfloat16* __restrict__ A,
                  const __hip_bfloat16* __restrict__ B,
                  const float* __restrict__ fb,
                  const float* __restrict__ bb,
                  float* __restrict__ S,
                  const int* __restrict__ hdr,
                  int K, int MT) {
    const int M = hdr[0], Nf = hdr[1];

    // XCD-aware bijective swizzle (m204), bm-fastest: ~15 consecutive blocks
    // share one B-tile (L2-resident 512KB).
    const int nwg = gridDim.x, orig = blockIdx.x;
    const int q = nwg >> 3, rr = nwg & 7;
    const int xcd = orig & 7, i8 = orig >> 3;
    const int wgid = (xcd < rr ? xcd * (q + 1) : rr * (q + 1) + (xcd - rr) * q) + i8;
    const int bm = wgid % MT, bn = wgid / MT;
    if (bm * 256 >= M) return;

    __shared__ __align__(16) char lds[2][2][32768];   // [buf][A/B][4 units x 8KB]

    const int tid = threadIdx.x, lane = tid & 63, wid = tid >> 6;
    const int wm = wid >> 2, wn = wid & 3;             // 2 x 4 waves

    f32x4 acc[8][4];
#pragma unroll
    for (int i = 0; i < 8; ++i)
#pragma unroll
        for (int j = 0; j < 4; ++j) acc[i][j] = (f32x4)0.f;

    const int Kb = K * 2;
    const char* gA = (const char*)A + (size_t)bm * 256 * Kb;
    const char* gB = (const char*)B + (size_t)bn * 256 * Kb;

    // staging geometry: thread -> (row, khalf); LDS dest linear tid*16
    const int srB  = ((((tid >> 5) << 4) | (tid & 15))) * Kb;  // row * rowbytes
    const int shh  = ((tid >> 4) & 1) << 4;                    // khalf * 16B
    const int sdst = tid << 4;

    // fragment-read offsets: two contiguous 512B segments per wave read
    const int ll   = (((lane >> 4) & 1) << 8) | ((lane & 15) << 4);
    const int ksu  = ((lane >> 5) & 1) << 13;
    const int aoff = ksu + ((wm * 8) << 9) + ll;   // + ks*16384 + mf*512
    const int boff = ksu + ((wn * 4) << 9) + ll;   // + ks*16384 + nf*512

    bf16x8 af[4], bfr[4];

#define STAGE_UNIT(nbuf, u, t) do {                                           \
    const int _go = (t) * 128 + ((u) << 5) + shh;                             \
    __builtin_amdgcn_global_load_lds(                                         \
        (const AS1 uint32_t*)(gA + srB + _go),                                \
        (AS3 uint32_t*)(&lds[nbuf][0][0] + ((u) << 13) + sdst), 16, 0, 0);    \
    __builtin_amdgcn_global_load_lds(                                         \
        (const AS1 uint32_t*)(gB + srB + _go),                                \
        (AS3 uint32_t*)(&lds[nbuf][1][0] + ((u) << 13) + sdst), 16, 0, 0);    \
} while (0)

#define READ_A(cbuf, MH, KS) do {                                             \
    const char* _p = &lds[cbuf][0][0] + aoff + (KS) * 16384 + (MH) * 2048;    \
    af[0] = *(const bf16x8*)(_p);                                             \
    af[1] = *(const bf16x8*)(_p + 512);                                       \
    af[2] = *(const bf16x8*)(_p + 1024);                                      \
    af[3] = *(const bf16x8*)(_p + 1536);                                      \
} while (0)

#define READ_B(cbuf, KS) do {                                                 \
    const char* _p = &lds[cbuf][1][0] + boff + (KS) * 16384;                  \
    bfr[0] = *(const bf16x8*)(_p);                                            \
    bfr[1] = *(const bf16x8*)(_p + 512);                                      \
    bfr[2] = *(const bf16x8*)(_p + 1024);                                     \
    bfr[3] = *(const bf16x8*)(_p + 1536);                                     \
} while (0)

#define MFMA16(MH) do {                                                       \
    __builtin_amdgcn_s_setprio(1);                                            \
    _Pragma("unroll")                                                         \
    for (int _i = 0; _i < 4; ++_i)                                            \
        _Pragma("unroll")                                                     \
        for (int _n = 0; _n < 4; ++_n)                                        \
            acc[(MH) * 4 + _i][_n] = __builtin_amdgcn_mfma_f32_16x16x32_bf16( \
                af[_i], bfr[_n], acc[(MH) * 4 + _i][_n], 0, 0, 0);            \
    __builtin_amdgcn_s_setprio(0);                                            \
} while (0)

#define GATE4() asm volatile("s_waitcnt vmcnt(4)" ::: "memory")
#define GATE0() asm volatile("s_waitcnt vmcnt(0)" ::: "memory")
#define BAR() do { __builtin_amdgcn_s_barrier(); __builtin_amdgcn_sched_barrier(0); } while (0)

    const int NT = K >> 6;   // K-tiles of 64 (K=1024 -> 16)

    // prologue: stage tile 0 (issue order u0..u3 -> oldest 4 loads = units 0,1)
    STAGE_UNIT(0, 0, 0); STAGE_UNIT(0, 1, 0); STAGE_UNIT(0, 2, 0); STAGE_UNIT(0, 3, 0);

#pragma unroll 2
    for (int t = 0; t < NT - 1; ++t) {
        const int cur = t & 1, nxt = cur ^ 1;
        // phase 0: needs units 0,1 (ks=0); 4 newer loads (units 2,3) may fly
        GATE4(); BAR();
        READ_A(cur, 0, 0); READ_B(cur, 0);
        STAGE_UNIT(nxt, 0, t + 1);
        MFMA16(0);
        // phase 1: same units, no gate
        BAR();
        READ_A(cur, 1, 0);
        STAGE_UNIT(nxt, 1, t + 1);
        MFMA16(1);
        // phase 2: needs units 2,3 (ks=1); 4 newer loads (nxt u0,u1) may fly
        GATE4(); BAR();
        READ_A(cur, 0, 1); READ_B(cur, 1);
        STAGE_UNIT(nxt, 2, t + 1);
        MFMA16(0);
        // phase 3
        BAR();
        READ_A(cur, 1, 1);
        STAGE_UNIT(nxt, 3, t + 1);
        MFMA16(1);
    }
    {   // peeled last tile: no staging; final gate must drain (vmcnt 0)
        const int cur = (NT - 1) & 1;
        GATE4(); BAR();
        READ_A(cur, 0, 0); READ_B(cur, 0);
        MFMA16(0);
        BAR();
        READ_A(cur, 1, 0);
        MFMA16(1);
        GATE0(); BAR();
        READ_A(cur, 0, 1); READ_B(cur, 1);
        MFMA16(0);
        BAR();
        READ_A(cur, 1, 1);
        MFMA16(1);
    }

    // epilogue: bias + exp + 64-col row partials + atomic
    float fbv[4], bbv[4];
#pragma unroll
    for (int nf = 0; nf < 4; ++nf) {
        const int v = bn * 256 + wn * 64 + nf * 16 + (lane & 15);
        fbv[nf] = fb[v]; bbv[nf] = bb[v];
    }
#pragma unroll
    for (int mf = 0; mf < 8; ++mf) {
#pragma unroll
        for (int j = 0; j < 4; ++j) {
            const int m = bm * 256 + wm * 128 + mf * 16 + ((lane >> 4) << 2) + j;
            if (m >= M) continue;   // uniform within each 16-lane shuffle group
            const bool isf = m < Nf;
            float ps = 0.f;
#pragma unroll
            for (int nf = 0; nf < 4; ++nf) {
                const float logit = acc[mf][nf][j] + (isf ? fbv[nf] : bbv[nf]);
                ps += exp2f(logit * LOG2E);
            }
#pragma unroll
            for (int s = 1; s < 16; s <<= 1) ps += __shfl_xor(ps, s);
            if ((lane & 15) == 0) atomicAdd(&S[m], ps);
        }
    }
#undef STAGE_UNIT
#undef READ_A
#undef READ_B
#undef MFMA16
#undef GATE4
#undef GATE0
#undef BAR
}

// ---------------- fallback (ws too small for Wb): simple 128^2, W f32 in-stage conv ----------------
__global__ __launch_bounds__(256, 2)
void gemm_lse_fb(const __hip_bfloat16* __restrict__ A, const float* __restrict__ Bf,
                 const float* __restrict__ fb, const float* __restrict__ bb,
                 float* __restrict__ S, const int* __restrict__ hdr, int K) {
    const int M = hdr[0], Nf = hdr[1];
    const int bm = blockIdx.y, bn = blockIdx.x;
    if (bm * 128 >= M) return;
    __shared__ __align__(16) char lA[8192];
    __shared__ __align__(16) char lB[8192];
    const int tid = threadIdx.x, wid = tid >> 6, lane = tid & 63;
    const int wm = wid >> 1, wn = wid & 1;
    f32x4 acc[4][4];
#pragma unroll
    for (int i = 0; i < 4; ++i)
#pragma unroll
        for (int j = 0; j < 4; ++j) acc[i][j] = (f32x4)0.f;
    const char* gA = (const char*)A + (size_t)bm * 128 * K * 2;
    const int Kb = K * 2;
    int srow[2], skg[2];
#pragma unroll
    for (int j = 0; j < 2; ++j) {
        const int i = j * 256 + tid;
        srow[j] = ((i >> 6) << 4) | (i & 15);
        skg[j] = (i >> 4) & 3;
    }
    for (int kt = 0; kt < (K >> 5); ++kt) {
        __syncthreads();
#pragma unroll
        for (int j = 0; j < 2; ++j) {
            const int i = j * 256 + tid;
            __builtin_amdgcn_global_load_lds(
                (const AS1 uint32_t*)(gA + (size_t)srow[j] * Kb + (kt << 6) + skg[j] * 16),
                (AS3 uint32_t*)(lA + i * 16), 16, 0, 0);
            const float* src = Bf + (size_t)(bn * 128 + srow[j]) * K + (kt << 5) + skg[j] * 8;
            float4 v0 = *(const float4*)src, v1 = *(const float4*)(src + 4);
            union { __hip_bfloat16 h[8]; int4 i4; } u;
            u.h[0] = __float2bfloat16(v0.x); u.h[1] = __float2bfloat16(v0.y);
            u.h[2] = __float2bfloat16(v0.z); u.h[3] = __float2bfloat16(v0.w);
            u.h[4] = __float2bfloat16(v1.x); u.h[5] = __float2bfloat16(v1.y);
            u.h[6] = __float2bfloat16(v1.z); u.h[7] = __float2bfloat16(v1.w);
            *(int4*)(lB + i * 16) = u.i4;
        }
        __syncthreads();
        bf16x8 a[4], b[4];
        const char* pa = lA + (lane << 4);
        const char* pb = lB + (lane << 4);
#pragma unroll
        for (int mf = 0; mf < 4; ++mf) a[mf] = *(const bf16x8*)(pa + ((wm * 4 + mf) << 10));
#pragma unroll
        for (int nf = 0; nf < 4; ++nf) b[nf] = *(const bf16x8*)(pb + ((wn * 4 + nf) << 10));
#pragma unroll
        for (int mf = 0; mf < 4; ++mf)
#pragma unroll
            for (int nf = 0; nf < 4; ++nf)
                acc[mf][nf] = __builtin_amdgcn_mfma_f32_16x16x32_bf16(a[mf], b[nf], acc[mf][nf], 0, 0, 0);
    }
    float fbv[4], bbv[4];
#pragma unroll
    for (int nf = 0; nf < 4; ++nf) {
        int v = bn * 128 + wn * 64 + nf * 16 + (lane & 15);
        fbv[nf] = fb[v]; bbv[nf] = bb[v];
    }
#pragma unroll
    for (int mf = 0; mf < 4; ++mf) {
#pragma unroll
        for (int j = 0; j < 4; ++j) {
            int m = bm * 128 + wm * 64 + mf * 16 + (lane >> 4) * 4 + j;
            if (m >= M) continue;
            const bool isf = m < Nf;
            float ps = 0.f;
#pragma unroll
            for (int nf = 0; nf < 4; ++nf) {
                float logit = acc[mf][nf][j] + (isf ? fbv[nf] : bbv[nf]);
                ps += exp2f(logit * LOG2E);
            }
#pragma unroll
            for (int s = 1; s < 16; s <<= 1) ps += __shfl_xor(ps, s);
            if ((lane & 15) == 0) atomicAdd(&S[m], ps);
        }
    }
}

// ---------------- gold logits (exact f32) ----------------
__global__ void gold_kernel(const float* __restrict__ hs,
                            const float* __restrict__ W,
                            const float* __restrict__ fb,
                            const float* __restrict__ bb,
                            const int* __restrict__ row_ctx,
                            const int* __restrict__ row_tok,
                            const int* __restrict__ hdr,
                            float* __restrict__ goldv, int D2, int D) {
    const int m = blockIdx.x;
    const int M = hdr[0];
    if (m >= M) return;
    const int Nf = hdr[1];
    const int ctx = row_ctx[m], tok = row_tok[m];
    const float4* h = (const float4*)(hs + (size_t)ctx * D2 + (m < Nf ? 0 : D));
    const float4* w = (const float4*)(W + (size_t)tok * D);
    float s = 0.f;
    for (int i = threadIdx.x; i < D / 4; i += blockDim.x) {
        float4 a = h[i], b = w[i];
        s += a.x * b.x + a.y * b.y + a.z * b.z + a.w * b.w;
    }
#pragma unroll
    for (int d = 1; d < 64; d <<= 1) s += __shfl_xor(s, d);
    __shared__ float wsum[4];
    const int wid = threadIdx.x >> 6, lane = threadIdx.x & 63;
    if (lane == 0) wsum[wid] = s;
    __syncthreads();
    if (threadIdx.x == 0) {
        float tot = wsum[0] + wsum[1] + wsum[2] + wsum[3];
        tot += (m < Nf ? fb[tok] : bb[tok]);
        goldv[m] = tot;
    }
}

// ---------------- final reduce ----------------
__global__ void final_kernel(const float* __restrict__ S,
                             const float* __restrict__ goldv,
                             const int* __restrict__ hdr,
                             const float* __restrict__ fhdr,
                             float* __restrict__ out) {
    const int M = hdr[0];
    float s = 0.f;
    for (int m = threadIdx.x; m < M; m += blockDim.x)
        s += logf(S[m]) - goldv[m];
#pragma unroll
    for (int d = 1; d < 64; d <<= 1) s += __shfl_xor(s, d);
    __shared__ float wsum[4];
    const int wid = threadIdx.x >> 6, lane = threadIdx.x & 63;
    if (lane == 0) wsum[wid] = s;
    __syncthreads();
    if (threadIdx.x == 0)
        out[0] = (wsum[0] + wsum[1] + wsum[2] + wsum[3]) / fhdr[0];
}

extern "C" void kernel_launch(void* const* d_in, const int* in_sizes, int n_in,
                              void* d_out, int out_size, void* d_ws, size_t ws_size,
                              hipStream_t stream) {
    const float* hs  = (const float*)d_in[0];
    const float* W   = (const float*)d_in[1];
    const float* fb  = (const float*)d_in[2];
    const float* bb  = (const float*)d_in[3];
    const int* sent  = (const int*)d_in[4];
    const int* bs    = (const int*)d_in[5];
    const int total  = in_sizes[4];
    const int T      = in_sizes[5];
    const int V      = in_sizes[2];
    const int D      = in_sizes[1] / V;
    const int D2     = in_sizes[0] / total;
    const int Mcap   = ((2 * total) + 255) & ~255;   // 256-aligned upper bound
    const int MT     = Mcap / 256;
    const int NN     = V / 256;

    char* p = (char*)d_ws;
    int*   hdr     = (int*)p;            p += 256;
    float* fhdr    = (float*)p;          p += 256;
    int*   row_ctx = (int*)p;            p += (size_t)Mcap * 4;
    int*   row_tok = (int*)p;            p += (size_t)Mcap * 4;
    float* S       = (float*)p;          p += (size_t)Mcap * 4;
    float* goldv   = (float*)p;          p += (size_t)Mcap * 4;
    __hip_bfloat16* Hc = (__hip_bfloat16*)p; p += (size_t)Mcap * D * 2;
    __hip_bfloat16* Wb = (__hip_bfloat16*)p;
    const size_t need_wb = (size_t)(p - (char*)d_ws) + (size_t)V * D * 2;

    prep_kernel<<<1, 256, 0, stream>>>(bs, T, sent, hdr, fhdr, row_ctx, row_tok);
    gather_kernel<<<Mcap, 256, 0, stream>>>(hs, row_ctx, hdr, Hc, S, D2, D);

    if (ws_size >= need_wb) {
        long n4 = (long)V * D / 4;
        wconv_kernel<<<(int)((n4 + 255) / 256), 256, 0, stream>>>(W, Wb, n4);
        gemm_lse_256<<<NN * MT, 512, 0, stream>>>(Hc, Wb, fb, bb, S, hdr, D, MT);
    } else {
        dim3 grid(V / 128, Mcap / 128);
        gemm_lse_fb<<<grid, 256, 0, stream>>>(Hc, W, fb, bb, S, hdr, D);
    }

    gold_kernel<<<Mcap, 256, 0, stream>>>(hs, W, fb, bb, row_ctx, row_tok, hdr, goldv, D2, D);
    final_kernel<<<1, 256, 0, stream>>>(S, goldv, hdr, fhdr, (float*)d_out);
}